// Round 12
// baseline (226.069 us; speedup 1.0000x reference)
//
#include <hip/hip_runtime.h>

typedef unsigned int uint;
typedef unsigned short ushort;
typedef __attribute__((ext_vector_type(8))) short bf16x8;
typedef __attribute__((ext_vector_type(4))) float f32x4;

#define N_NODES 100000
#define N_EDGES 3200000
#define N_PAIRS 1000000
#define NBLK (N_NODES / 16)                                // 6250 exact

#define BUCK_SHIFT 8
#define BUCK_NODES 256
#define NBUCK ((N_NODES + BUCK_NODES - 1) / BUCK_NODES)    // 391
#define CAP 8704                                           // mean 8192, +5.7 sigma
#define CH 8192                                            // edges per binning block
#define NCHB ((N_EDGES + CH - 1) / CH)                     // 391
#define EPL (CH / 256)                                     // 32 edges per thread

__device__ __forceinline__ float bf_lo(uint u) { return __uint_as_float(u << 16); }
__device__ __forceinline__ float bf_hi(uint u) { return __uint_as_float(u & 0xFFFF0000u); }
__device__ __forceinline__ ushort f2bf(float f) {
  uint u = __float_as_uint(f);
  return (ushort)((u + 0x7FFF + ((u >> 16) & 1)) >> 16);   // round-nearest-even
}
__device__ __forceinline__ uint pack2bf(float lo, float hi) {
  return (uint)f2bf(lo) | ((uint)f2bf(hi) << 16);
}

// ---------------- prep: x -> bf16 (vectorized), W -> transposed bf16, cursors

__global__ void __launch_bounds__(256) k_prep(
    const float* __restrict__ x,
    const float* __restrict__ Wl1, const float* __restrict__ Wr1,
    const float* __restrict__ Wl2, const float* __restrict__ Wr2,
    ushort* __restrict__ xb, ushort* __restrict__ W1T, ushort* __restrict__ W2T,
    int* __restrict__ woff)
{
  int t = blockIdx.x * blockDim.x + threadIdx.x;
  if (t < N_NODES * 8) {                         // 4 floats -> one 8B store
    float4 f = ((const float4*)x)[t];
    uint2 o;
    o.x = pack2bf(f.x, f.y);
    o.y = pack2bf(f.z, f.w);
    ((uint2*)xb)[t] = o;
  }
  if (t < 4096) {
    int col = t >> 6, f = t & 63;
    float w = (f < 32) ? Wl1[f * 64 + col] : Wr1[(f - 32) * 64 + col];
    W1T[col * 64 + f] = f2bf(w);
  }
  if (t < 8192) {
    int col = t >> 7, f = t & 127;
    float w = (f < 64) ? Wl2[f * 64 + col] : Wr2[(f - 64) * 64 + col];
    W2T[col * 128 + f] = f2bf(w);
  }
  if (t < NBUCK) woff[t] = t * CAP;
}

// ---------------- binning: sort-in-LDS, coalesced run copy-out (R10, proven) --

__global__ void __launch_bounds__(256) k_binning(
    const int* __restrict__ src, const int* __restrict__ dst,
    int* __restrict__ woff, int* __restrict__ bucket_data)
{
  __shared__ uint sorted[CH];                    // 32 KB
  __shared__ int hist[NBUCK];
  __shared__ int pfx[NBUCK];
  __shared__ int off[NBUCK];
  __shared__ int rbase[NBUCK];
  int t = threadIdx.x;
  int w = t >> 6, lane = t & 63;
  int lo = blockIdx.x * CH;
  int hi = lo + CH; if (hi > N_EDGES) hi = N_EDGES;
  for (int i = t; i < NBUCK; i += 256) hist[i] = 0;
  __syncthreads();
  int dreg[EPL], sreg[EPL];                      // register-cached edges (rule #20)
#pragma unroll
  for (int it = 0; it < EPL; ++it) {
    int e = lo + t + it * 256;
    int dv = -1, sv = 0;
    if (e < hi) { dv = dst[e]; sv = src[e]; }
    dreg[it] = dv; sreg[it] = sv;
    if (dv >= 0) atomicAdd(&hist[dv >> BUCK_SHIFT], 1);
  }
  __syncthreads();
  if (w == 0) {                                  // exclusive prefix over 391 bins
    int carry = 0;
    for (int c = 0; c < (NBUCK + 63) / 64; ++c) {
      int i = c * 64 + lane;
      int v = (i < NBUCK) ? hist[i] : 0;
      int x = v;
#pragma unroll
      for (int o = 1; o < 64; o <<= 1) {
        int y = __shfl_up(x, o);
        if (lane >= o) x += y;
      }
      if (i < NBUCK) pfx[i] = carry + x - v;
      carry += __shfl(x, 63);
    }
  }
  __syncthreads();
  for (int i = t; i < NBUCK; i += 256) {
    off[i] = pfx[i];
    int h = hist[i];
    rbase[i] = h ? atomicAdd(&woff[i], h) : 0;
  }
  __syncthreads();
#pragma unroll
  for (int it = 0; it < EPL; ++it) {             // scatter into sorted LDS
    int dv = dreg[it];
    if (dv >= 0) {
      int b = dv >> BUCK_SHIFT;
      int slot = atomicAdd(&off[b], 1);
      sorted[slot] = ((uint)sreg[it] << BUCK_SHIFT) | (uint)(dv & (BUCK_NODES - 1));
    }
  }
  __syncthreads();
  for (int b = w; b < NBUCK; b += 4) {           // coalesced run copy-out
    int h = hist[b];
    int s = pfx[b];
    int g = rbase[b];
    int lim = (b + 1) * CAP - g;                 // safety; never binds
    if (h > lim) h = lim;
    for (int j = lane; j < h; j += 64)
      bucket_data[g + j] = sorted[s + j];
  }
}

// ---------------- per-bucket counting sort -> bucket-local CSR ----------------

__global__ void __launch_bounds__(512) k_bucket_csr(
    const int* __restrict__ woff, const int* __restrict__ bucket_data,
    int* __restrict__ csr, int* __restrict__ row_beg, int* __restrict__ row_end)
{
  __shared__ int hist[BUCK_NODES];
  __shared__ int sc[BUCK_NODES];
  __shared__ int offs[BUCK_NODES];
  int b = blockIdx.x;
  int t = threadIdx.x;
  int base = b * CAP;
  int cnt = woff[b] - base;
  const int* bd = bucket_data + base;
  if (t < BUCK_NODES) hist[t] = 0;
  __syncthreads();
  for (int i = t; i < cnt; i += 512) atomicAdd(&hist[bd[i] & (BUCK_NODES - 1)], 1);
  __syncthreads();
  if (t < BUCK_NODES) sc[t] = hist[t];
  __syncthreads();
  for (int off = 1; off < BUCK_NODES; off <<= 1) {
    int u = 0;
    if (t < BUCK_NODES && t >= off) u = sc[t - off];
    __syncthreads();
    if (t < BUCK_NODES) sc[t] += u;
    __syncthreads();
  }
  if (t < BUCK_NODES) {
    int start = base + sc[t] - hist[t];          // exclusive within bucket
    offs[t] = start;
    int node = b * BUCK_NODES + t;
    if (node < N_NODES) { row_beg[node] = start; row_end[node] = start + hist[t]; }
  }
  __syncthreads();
  for (int i = t; i < cnt; i += 512) {
    int pv = bd[i];
    int pos = atomicAdd(&offs[pv & (BUCK_NODES - 1)], 1);
    csr[pos] = pv >> BUCK_SHIFT;
  }
}

// ---------------- fused layer 1: gather-mean (16 waves) + MFMA (4 waves) -----
// Block = 16 nodes; wave w gathers node b*16+w (R10 gather1 loop, verbatim),
// writes mean row to LDS (padded stride 5, plain writes). After barrier,
// waves 0-3 each compute output quadrant j=w of the 16-node MFMA tile.

__global__ void __launch_bounds__(1024) k_layer1f(
    const uint4* __restrict__ xb4, const ushort* __restrict__ xb,
    const int* __restrict__ row_beg, const int* __restrict__ row_end,
    const int* __restrict__ csr, const ushort* __restrict__ W1T,
    const float* __restrict__ bl, ushort* __restrict__ h1b)
{
  __shared__ uint4 mean_lds[16 * 5];             // node row stride 5 (pad)
  int b = blockIdx.x;
  int t = threadIdx.x;
  int w = t >> 6, lane = t & 63;
  int n = b * 16 + w;
  int slot = lane >> 2;
  int fq = lane & 3;
  int beg = row_beg[n], end = row_end[n];
  int deg = end - beg;
  float s0 = 0.f, s1 = 0.f, s2 = 0.f, s3 = 0.f, s4 = 0.f, s5 = 0.f, s6 = 0.f, s7 = 0.f;
  int i = beg;
  for (; i + 31 < end; i += 32) {                // 32 neighbors, 2 gathers/lane
    int n0 = csr[i + slot];
    int n1 = csr[i + 16 + slot];
    uint4 a = xb4[n0 * 4 + fq];
    uint4 bb = xb4[n1 * 4 + fq];
    s0 += bf_lo(a.x); s1 += bf_hi(a.x); s2 += bf_lo(a.y); s3 += bf_hi(a.y);
    s4 += bf_lo(a.z); s5 += bf_hi(a.z); s6 += bf_lo(a.w); s7 += bf_hi(a.w);
    s0 += bf_lo(bb.x); s1 += bf_hi(bb.x); s2 += bf_lo(bb.y); s3 += bf_hi(bb.y);
    s4 += bf_lo(bb.z); s5 += bf_hi(bb.z); s6 += bf_lo(bb.w); s7 += bf_hi(bb.w);
  }
  for (; i < end; i += 16) {
    if (i + slot < end) {
      uint4 a = xb4[csr[i + slot] * 4 + fq];
      s0 += bf_lo(a.x); s1 += bf_hi(a.x); s2 += bf_lo(a.y); s3 += bf_hi(a.y);
      s4 += bf_lo(a.z); s5 += bf_hi(a.z); s6 += bf_lo(a.w); s7 += bf_hi(a.w);
    }
  }
#pragma unroll
  for (int off = 4; off <= 32; off <<= 1) {
    s0 += __shfl_xor(s0, off); s1 += __shfl_xor(s1, off);
    s2 += __shfl_xor(s2, off); s3 += __shfl_xor(s3, off);
    s4 += __shfl_xor(s4, off); s5 += __shfl_xor(s5, off);
    s6 += __shfl_xor(s6, off); s7 += __shfl_xor(s7, off);
  }
  if (slot == 0) {
    float invd = (deg > 0) ? 1.f / (float)deg : 0.f;
    uint4 o;
    o.x = pack2bf(s0 * invd, s1 * invd);
    o.y = pack2bf(s2 * invd, s3 * invd);
    o.z = pack2bf(s4 * invd, s5 * invd);
    o.w = pack2bf(s6 * invd, s7 * invd);
    mean_lds[w * 5 + fq] = o;
  }
  __syncthreads();
  if (w < 4) {                                   // MFMA quadrant j = w
    int lc = lane & 15, lg = lane >> 4;
    bf16x8 bfr0 = *(const bf16x8*)(W1T + (w * 16 + lc) * 64 + lg * 8);
    bf16x8 bfr1 = *(const bf16x8*)(W1T + (w * 16 + lc) * 64 + 32 + lg * 8);
    float bb = bl[w * 16 + lc];
    f32x4 c; c[0] = bb; c[1] = bb; c[2] = bb; c[3] = bb;
    bf16x8 a0 = *(const bf16x8*)&mean_lds[lc * 5 + lg];
    bf16x8 a1 = *(const bf16x8*)(xb + (b * 16 + lc) * 32 + lg * 8);
    c = __builtin_amdgcn_mfma_f32_16x16x32_bf16(a0, bfr0, c, 0, 0, 0);
    c = __builtin_amdgcn_mfma_f32_16x16x32_bf16(a1, bfr1, c, 0, 0, 0);
#pragma unroll
    for (int r = 0; r < 4; ++r) {
      int node = b * 16 + lg * 4 + r;
      h1b[node * 64 + w * 16 + lc] = f2bf(fmaxf(c[r], 0.f));
    }
  }
}

// ---------------- fused layer 2: gather-mean + MFMA + u/v projection ---------

__global__ void __launch_bounds__(1024) k_layer2f(
    const uint4* __restrict__ hb4, const ushort* __restrict__ h1b,
    const int* __restrict__ row_beg, const int* __restrict__ row_end,
    const int* __restrict__ csr, const ushort* __restrict__ W2T,
    const float* __restrict__ bl, const float* __restrict__ Wh,
    float* __restrict__ u, float* __restrict__ v)
{
  __shared__ uint4 m2[16 * 9];                   // node row stride 9 (pad)
  __shared__ float pu_lds[4 * 16];
  __shared__ float pv_lds[4 * 16];
  int b = blockIdx.x;
  int t = threadIdx.x;
  int w = t >> 6, lane = t & 63;
  int n = b * 16 + w;
  int slot = lane >> 3;
  int fq = lane & 7;
  int beg = row_beg[n], end = row_end[n];
  int deg = end - beg;
  float s0 = 0.f, s1 = 0.f, s2 = 0.f, s3 = 0.f, s4 = 0.f, s5 = 0.f, s6 = 0.f, s7 = 0.f;
  int i = beg;
  for (; i + 31 < end; i += 32) {                // 32 neighbors, 4 gathers/lane
    int n0 = csr[i + slot];
    int n1 = csr[i + 8 + slot];
    int n2 = csr[i + 16 + slot];
    int n3 = csr[i + 24 + slot];
    uint4 a = hb4[n0 * 8 + fq];
    uint4 bb = hb4[n1 * 8 + fq];
    uint4 c = hb4[n2 * 8 + fq];
    uint4 d = hb4[n3 * 8 + fq];
    s0 += bf_lo(a.x); s1 += bf_hi(a.x); s2 += bf_lo(a.y); s3 += bf_hi(a.y);
    s4 += bf_lo(a.z); s5 += bf_hi(a.z); s6 += bf_lo(a.w); s7 += bf_hi(a.w);
    s0 += bf_lo(bb.x); s1 += bf_hi(bb.x); s2 += bf_lo(bb.y); s3 += bf_hi(bb.y);
    s4 += bf_lo(bb.z); s5 += bf_hi(bb.z); s6 += bf_lo(bb.w); s7 += bf_hi(bb.w);
    s0 += bf_lo(c.x); s1 += bf_hi(c.x); s2 += bf_lo(c.y); s3 += bf_hi(c.y);
    s4 += bf_lo(c.z); s5 += bf_hi(c.z); s6 += bf_lo(c.w); s7 += bf_hi(c.w);
    s0 += bf_lo(d.x); s1 += bf_hi(d.x); s2 += bf_lo(d.y); s3 += bf_hi(d.y);
    s4 += bf_lo(d.z); s5 += bf_hi(d.z); s6 += bf_lo(d.w); s7 += bf_hi(d.w);
  }
  for (; i < end; i += 8) {
    if (i + slot < end) {
      uint4 a = hb4[csr[i + slot] * 8 + fq];
      s0 += bf_lo(a.x); s1 += bf_hi(a.x); s2 += bf_lo(a.y); s3 += bf_hi(a.y);
      s4 += bf_lo(a.z); s5 += bf_hi(a.z); s6 += bf_lo(a.w); s7 += bf_hi(a.w);
    }
  }
#pragma unroll
  for (int off = 8; off <= 32; off <<= 1) {
    s0 += __shfl_xor(s0, off); s1 += __shfl_xor(s1, off);
    s2 += __shfl_xor(s2, off); s3 += __shfl_xor(s3, off);
    s4 += __shfl_xor(s4, off); s5 += __shfl_xor(s5, off);
    s6 += __shfl_xor(s6, off); s7 += __shfl_xor(s7, off);
  }
  if (slot == 0) {
    float invd = (deg > 0) ? 1.f / (float)deg : 0.f;
    uint4 o;
    o.x = pack2bf(s0 * invd, s1 * invd);
    o.y = pack2bf(s2 * invd, s3 * invd);
    o.z = pack2bf(s4 * invd, s5 * invd);
    o.w = pack2bf(s6 * invd, s7 * invd);
    m2[w * 9 + fq] = o;
  }
  __syncthreads();
  if (w < 4) {                                   // MFMA quadrant j = w + dot
    int lc = lane & 15, lg = lane >> 4;
    bf16x8 bfr0 = *(const bf16x8*)(W2T + (w * 16 + lc) * 128 + lg * 8);
    bf16x8 bfr1 = *(const bf16x8*)(W2T + (w * 16 + lc) * 128 + 32 + lg * 8);
    bf16x8 bfr2 = *(const bf16x8*)(W2T + (w * 16 + lc) * 128 + 64 + lg * 8);
    bf16x8 bfr3 = *(const bf16x8*)(W2T + (w * 16 + lc) * 128 + 96 + lg * 8);
    float bb = bl[w * 16 + lc];
    f32x4 c; c[0] = bb; c[1] = bb; c[2] = bb; c[3] = bb;
    bf16x8 a0 = *(const bf16x8*)&m2[lc * 9 + lg];
    bf16x8 a1 = *(const bf16x8*)&m2[lc * 9 + 4 + lg];
    bf16x8 a2 = *(const bf16x8*)(h1b + (b * 16 + lc) * 64 + lg * 8);
    bf16x8 a3 = *(const bf16x8*)(h1b + (b * 16 + lc) * 64 + 32 + lg * 8);
    c = __builtin_amdgcn_mfma_f32_16x16x32_bf16(a0, bfr0, c, 0, 0, 0);
    c = __builtin_amdgcn_mfma_f32_16x16x32_bf16(a1, bfr1, c, 0, 0, 0);
    c = __builtin_amdgcn_mfma_f32_16x16x32_bf16(a2, bfr2, c, 0, 0, 0);
    c = __builtin_amdgcn_mfma_f32_16x16x32_bf16(a3, bfr3, c, 0, 0, 0);
    float wu = Wh[w * 16 + lc];
    float wv = Wh[64 + w * 16 + lc];
    float r0 = fmaxf(c[0], 0.f), r1 = fmaxf(c[1], 0.f);
    float r2 = fmaxf(c[2], 0.f), r3 = fmaxf(c[3], 0.f);
    float pu0 = r0 * wu, pv0 = r0 * wv;
    float pu1 = r1 * wu, pv1 = r1 * wv;
    float pu2 = r2 * wu, pv2 = r2 * wv;
    float pu3 = r3 * wu, pv3 = r3 * wv;
#pragma unroll
    for (int off = 1; off <= 8; off <<= 1) {
      pu0 += __shfl_xor(pu0, off); pv0 += __shfl_xor(pv0, off);
      pu1 += __shfl_xor(pu1, off); pv1 += __shfl_xor(pv1, off);
      pu2 += __shfl_xor(pu2, off); pv2 += __shfl_xor(pv2, off);
      pu3 += __shfl_xor(pu3, off); pv3 += __shfl_xor(pv3, off);
    }
    if (lc == 0) {
      pu_lds[w * 16 + lg * 4 + 0] = pu0; pv_lds[w * 16 + lg * 4 + 0] = pv0;
      pu_lds[w * 16 + lg * 4 + 1] = pu1; pv_lds[w * 16 + lg * 4 + 1] = pv1;
      pu_lds[w * 16 + lg * 4 + 2] = pu2; pv_lds[w * 16 + lg * 4 + 2] = pv2;
      pu_lds[w * 16 + lg * 4 + 3] = pu3; pv_lds[w * 16 + lg * 4 + 3] = pv3;
    }
  }
  __syncthreads();
  if (t < 16) {
    int node = b * 16 + t;
    u[node] = pu_lds[t] + pu_lds[16 + t] + pu_lds[32 + t] + pu_lds[48 + t];
    v[node] = pv_lds[t] + pv_lds[16 + t] + pv_lds[32 + t] + pv_lds[48 + t];
  }
}

// ---------------- edge scorer: table lookup only ----------------

__global__ void __launch_bounds__(256) k_edge_lite(
    const int2* __restrict__ pairs, const float* __restrict__ u,
    const float* __restrict__ v, const float* __restrict__ bh,
    float* __restrict__ out)
{
  int e = blockIdx.x * blockDim.x + threadIdx.x;
  if (e < N_PAIRS) {
    int2 pr = pairs[e];
    out[e] = u[pr.x] + v[pr.y] + bh[0];
  }
}

// ---------------- launch ----------------

extern "C" void kernel_launch(void* const* d_in, const int* in_sizes, int n_in,
                              void* d_out, int out_size, void* d_ws, size_t ws_size,
                              hipStream_t stream)
{
  const float* x   = (const float*)d_in[0];
  const int*   ei  = (const int*)d_in[1];
  const int* pairs = (const int*)d_in[2];
  const float* Wl1 = (const float*)d_in[3];
  const float* bl1 = (const float*)d_in[4];
  const float* Wr1 = (const float*)d_in[5];
  const float* Wl2 = (const float*)d_in[6];
  const float* bl2 = (const float*)d_in[7];
  const float* Wr2 = (const float*)d_in[8];
  const float* Wh  = (const float*)d_in[9];
  const float* bh  = (const float*)d_in[10];
  float* out = (float*)d_out;

  const int* src = ei;             // edge_index[0]
  const int* dst = ei + N_EDGES;   // edge_index[1]

  char* p = (char*)d_ws;
  auto alloc = [&](size_t bytes) {
    char* r = p;
    p += (bytes + 255) & ~(size_t)255;
    return r;
  };
  int*    woff        = (int*)alloc((size_t)NBUCK * 4);
  int*    bucket_data = (int*)alloc((size_t)NBUCK * CAP * 4);     // 13.6 MB
  int*    csr         = (int*)alloc((size_t)NBUCK * CAP * 4);     // 13.6 MB
  int*    row_beg     = (int*)alloc((size_t)N_NODES * 4);
  int*    row_end     = (int*)alloc((size_t)N_NODES * 4);
  ushort* xb          = (ushort*)alloc((size_t)N_NODES * 32 * 2); // 6.4 MB
  ushort* h1b         = (ushort*)alloc((size_t)N_NODES * 64 * 2); // 12.8 MB
  ushort* W1T         = (ushort*)alloc(64 * 64 * 2);
  ushort* W2T         = (ushort*)alloc(64 * 128 * 2);
  float*  uu          = (float*)alloc((size_t)N_NODES * 4);
  float*  vv          = (float*)alloc((size_t)N_NODES * 4);

  k_prep<<<(N_NODES * 8 + 255) / 256, 256, 0, stream>>>(
      x, Wl1, Wr1, Wl2, Wr2, xb, W1T, W2T, woff);
  k_binning<<<NCHB, 256, 0, stream>>>(src, dst, woff, bucket_data);
  k_bucket_csr<<<NBUCK, 512, 0, stream>>>(woff, bucket_data, csr, row_beg, row_end);

  k_layer1f<<<NBLK, 1024, 0, stream>>>(
      (const uint4*)xb, xb, row_beg, row_end, csr, W1T, bl1, h1b);
  k_layer2f<<<NBLK, 1024, 0, stream>>>(
      (const uint4*)h1b, h1b, row_beg, row_end, csr, W2T, bl2, Wh, uu, vv);
  k_edge_lite<<<(N_PAIRS + 255) / 256, 256, 0, stream>>>(
      (const int2*)pairs, uu, vv, bh, out);
}

// Round 14
// 208.180 us; speedup vs baseline: 1.0859x; 1.0859x over previous
//
#include <hip/hip_runtime.h>

typedef unsigned int uint;
typedef unsigned short ushort;
typedef __attribute__((ext_vector_type(8))) short bf16x8;
typedef __attribute__((ext_vector_type(4))) float f32x4;

#define N_NODES 100000
#define N_EDGES 3200000
#define N_PAIRS 1000000
#define N_TILES (N_NODES / 16)                             // 6250 exact

#define BUCK_SHIFT 8
#define BUCK_NODES 256
#define NBUCK ((N_NODES + BUCK_NODES - 1) / BUCK_NODES)    // 391
#define CAP 8704                                           // mean 8192, +5.7 sigma
#define CH 8192                                            // edges per binning block
#define NCHB ((N_EDGES + CH - 1) / CH)                     // 391
#define EPL (CH / 256)                                     // 32 edges per thread

__device__ __forceinline__ float bf_lo(uint u) { return __uint_as_float(u << 16); }
__device__ __forceinline__ float bf_hi(uint u) { return __uint_as_float(u & 0xFFFF0000u); }
__device__ __forceinline__ ushort f2bf(float f) {
  uint u = __float_as_uint(f);
  return (ushort)((u + 0x7FFF + ((u >> 16) & 1)) >> 16);   // round-nearest-even
}
__device__ __forceinline__ uint pack2bf(float lo, float hi) {
  return (uint)f2bf(lo) | ((uint)f2bf(hi) << 16);
}

// ---------------- prep: x -> bf16 (vectorized), W -> transposed bf16, cursors

__global__ void __launch_bounds__(256) k_prep(
    const float* __restrict__ x,
    const float* __restrict__ Wl1, const float* __restrict__ Wr1,
    const float* __restrict__ Wl2, const float* __restrict__ Wr2,
    ushort* __restrict__ xb, ushort* __restrict__ W1T, ushort* __restrict__ W2T,
    int* __restrict__ woff)
{
  int t = blockIdx.x * blockDim.x + threadIdx.x;
  if (t < N_NODES * 8) {                         // 4 floats -> one 8B store
    float4 f = ((const float4*)x)[t];
    uint2 o;
    o.x = pack2bf(f.x, f.y);
    o.y = pack2bf(f.z, f.w);
    ((uint2*)xb)[t] = o;
  }
  if (t < 4096) {
    int col = t >> 6, f = t & 63;
    float w = (f < 32) ? Wl1[f * 64 + col] : Wr1[(f - 32) * 64 + col];
    W1T[col * 64 + f] = f2bf(w);
  }
  if (t < 8192) {
    int col = t >> 7, f = t & 127;
    float w = (f < 64) ? Wl2[f * 64 + col] : Wr2[(f - 64) * 64 + col];
    W2T[col * 128 + f] = f2bf(w);
  }
  if (t < NBUCK) woff[t] = t * CAP;
}

// ---------------- binning: sort-in-LDS, coalesced run copy-out (R10, proven) --

__global__ void __launch_bounds__(256) k_binning(
    const int* __restrict__ src, const int* __restrict__ dst,
    int* __restrict__ woff, int* __restrict__ bucket_data)
{
  __shared__ uint sorted[CH];                    // 32 KB
  __shared__ int hist[NBUCK];
  __shared__ int pfx[NBUCK];
  __shared__ int off[NBUCK];
  __shared__ int rbase[NBUCK];
  int t = threadIdx.x;
  int w = t >> 6, lane = t & 63;
  int lo = blockIdx.x * CH;
  int hi = lo + CH; if (hi > N_EDGES) hi = N_EDGES;
  for (int i = t; i < NBUCK; i += 256) hist[i] = 0;
  __syncthreads();
  int dreg[EPL], sreg[EPL];                      // register-cached edges (rule #20)
#pragma unroll
  for (int it = 0; it < EPL; ++it) {
    int e = lo + t + it * 256;
    int dv = -1, sv = 0;
    if (e < hi) { dv = dst[e]; sv = src[e]; }
    dreg[it] = dv; sreg[it] = sv;
    if (dv >= 0) atomicAdd(&hist[dv >> BUCK_SHIFT], 1);
  }
  __syncthreads();
  if (w == 0) {                                  // exclusive prefix over 391 bins
    int carry = 0;
    for (int c = 0; c < (NBUCK + 63) / 64; ++c) {
      int i = c * 64 + lane;
      int v = (i < NBUCK) ? hist[i] : 0;
      int x = v;
#pragma unroll
      for (int o = 1; o < 64; o <<= 1) {
        int y = __shfl_up(x, o);
        if (lane >= o) x += y;
      }
      if (i < NBUCK) pfx[i] = carry + x - v;
      carry += __shfl(x, 63);
    }
  }
  __syncthreads();
  for (int i = t; i < NBUCK; i += 256) {
    off[i] = pfx[i];
    int h = hist[i];
    rbase[i] = h ? atomicAdd(&woff[i], h) : 0;
  }
  __syncthreads();
#pragma unroll
  for (int it = 0; it < EPL; ++it) {             // scatter into sorted LDS
    int dv = dreg[it];
    if (dv >= 0) {
      int b = dv >> BUCK_SHIFT;
      int slot = atomicAdd(&off[b], 1);
      sorted[slot] = ((uint)sreg[it] << BUCK_SHIFT) | (uint)(dv & (BUCK_NODES - 1));
    }
  }
  __syncthreads();
  for (int b = w; b < NBUCK; b += 4) {           // coalesced run copy-out
    int h = hist[b];
    int s = pfx[b];
    int g = rbase[b];
    int lim = (b + 1) * CAP - g;                 // safety; never binds
    if (h > lim) h = lim;
    for (int j = lane; j < h; j += 64)
      bucket_data[g + j] = sorted[s + j];
  }
}

// ---------------- per-bucket counting sort -> bucket-local CSR ----------------

__global__ void __launch_bounds__(512) k_bucket_csr(
    const int* __restrict__ woff, const int* __restrict__ bucket_data,
    int* __restrict__ csr, int* __restrict__ row_beg, int* __restrict__ row_end)
{
  __shared__ int hist[BUCK_NODES];
  __shared__ int sc[BUCK_NODES];
  __shared__ int offs[BUCK_NODES];
  int b = blockIdx.x;
  int t = threadIdx.x;
  int base = b * CAP;
  int cnt = woff[b] - base;
  const int* bd = bucket_data + base;
  if (t < BUCK_NODES) hist[t] = 0;
  __syncthreads();
  for (int i = t; i < cnt; i += 512) atomicAdd(&hist[bd[i] & (BUCK_NODES - 1)], 1);
  __syncthreads();
  if (t < BUCK_NODES) sc[t] = hist[t];
  __syncthreads();
  for (int off = 1; off < BUCK_NODES; off <<= 1) {
    int u = 0;
    if (t < BUCK_NODES && t >= off) u = sc[t - off];
    __syncthreads();
    if (t < BUCK_NODES) sc[t] += u;
    __syncthreads();
  }
  if (t < BUCK_NODES) {
    int start = base + sc[t] - hist[t];          // exclusive within bucket
    offs[t] = start;
    int node = b * BUCK_NODES + t;
    if (node < N_NODES) { row_beg[node] = start; row_end[node] = start + hist[t]; }
  }
  __syncthreads();
  for (int i = t; i < cnt; i += 512) {
    int pv = bd[i];
    int pos = atomicAdd(&offs[pv & (BUCK_NODES - 1)], 1);
    csr[pos] = pv >> BUCK_SHIFT;
  }
}

// ---------------- gather-mean kernels (wave per node, dwordx4 gathers) -------

// layer 1 mean: xb rows 64B (4 uint4). lane: slot=(l>>2) 0..15, fq=(l&3).
__global__ void __launch_bounds__(256) k_gather1(
    const uint4* __restrict__ xb4, const int* __restrict__ row_beg,
    const int* __restrict__ row_end, const int* __restrict__ csr,
    uint4* __restrict__ mean1)
{
  int gid = blockIdx.x * blockDim.x + threadIdx.x;
  int n = gid >> 6;
  int lane = threadIdx.x & 63;
  if (n >= N_NODES) return;
  int slot = lane >> 2;
  int fq = lane & 3;
  int beg = row_beg[n], end = row_end[n];
  int deg = end - beg;
  float s0 = 0.f, s1 = 0.f, s2 = 0.f, s3 = 0.f, s4 = 0.f, s5 = 0.f, s6 = 0.f, s7 = 0.f;
  int i = beg;
  for (; i + 31 < end; i += 32) {                // 32 neighbors, 2 gathers/lane
    int n0 = csr[i + slot];
    int n1 = csr[i + 16 + slot];
    uint4 a = xb4[n0 * 4 + fq];
    uint4 b = xb4[n1 * 4 + fq];
    s0 += bf_lo(a.x); s1 += bf_hi(a.x); s2 += bf_lo(a.y); s3 += bf_hi(a.y);
    s4 += bf_lo(a.z); s5 += bf_hi(a.z); s6 += bf_lo(a.w); s7 += bf_hi(a.w);
    s0 += bf_lo(b.x); s1 += bf_hi(b.x); s2 += bf_lo(b.y); s3 += bf_hi(b.y);
    s4 += bf_lo(b.z); s5 += bf_hi(b.z); s6 += bf_lo(b.w); s7 += bf_hi(b.w);
  }
  for (; i < end; i += 16) {
    if (i + slot < end) {
      uint4 a = xb4[csr[i + slot] * 4 + fq];
      s0 += bf_lo(a.x); s1 += bf_hi(a.x); s2 += bf_lo(a.y); s3 += bf_hi(a.y);
      s4 += bf_lo(a.z); s5 += bf_hi(a.z); s6 += bf_lo(a.w); s7 += bf_hi(a.w);
    }
  }
#pragma unroll
  for (int off = 4; off <= 32; off <<= 1) {
    s0 += __shfl_xor(s0, off); s1 += __shfl_xor(s1, off);
    s2 += __shfl_xor(s2, off); s3 += __shfl_xor(s3, off);
    s4 += __shfl_xor(s4, off); s5 += __shfl_xor(s5, off);
    s6 += __shfl_xor(s6, off); s7 += __shfl_xor(s7, off);
  }
  if (slot == 0) {
    float invd = (deg > 0) ? 1.f / (float)deg : 0.f;
    uint4 o;
    o.x = pack2bf(s0 * invd, s1 * invd);
    o.y = pack2bf(s2 * invd, s3 * invd);
    o.z = pack2bf(s4 * invd, s5 * invd);
    o.w = pack2bf(s6 * invd, s7 * invd);
    mean1[n * 4 + fq] = o;
  }
}

// layer 2 mean: h1b rows 128B (8 uint4). lane: slot=(l>>3) 0..7, fq=(l&7).
// 4 outstanding gathers per lane (32 neighbors per wave-iter).
__global__ void __launch_bounds__(256) k_gather2(
    const uint4* __restrict__ hb4, const int* __restrict__ row_beg,
    const int* __restrict__ row_end, const int* __restrict__ csr,
    uint4* __restrict__ mean2)
{
  int gid = blockIdx.x * blockDim.x + threadIdx.x;
  int n = gid >> 6;
  int lane = threadIdx.x & 63;
  if (n >= N_NODES) return;
  int slot = lane >> 3;
  int fq = lane & 7;
  int beg = row_beg[n], end = row_end[n];
  int deg = end - beg;
  float s0 = 0.f, s1 = 0.f, s2 = 0.f, s3 = 0.f, s4 = 0.f, s5 = 0.f, s6 = 0.f, s7 = 0.f;
  int i = beg;
  for (; i + 31 < end; i += 32) {                // 32 neighbors, 4 gathers/lane
    int n0 = csr[i + slot];
    int n1 = csr[i + 8 + slot];
    int n2 = csr[i + 16 + slot];
    int n3 = csr[i + 24 + slot];
    uint4 a = hb4[n0 * 8 + fq];
    uint4 b = hb4[n1 * 8 + fq];
    uint4 c = hb4[n2 * 8 + fq];
    uint4 d = hb4[n3 * 8 + fq];
    s0 += bf_lo(a.x); s1 += bf_hi(a.x); s2 += bf_lo(a.y); s3 += bf_hi(a.y);
    s4 += bf_lo(a.z); s5 += bf_hi(a.z); s6 += bf_lo(a.w); s7 += bf_hi(a.w);
    s0 += bf_lo(b.x); s1 += bf_hi(b.x); s2 += bf_lo(b.y); s3 += bf_hi(b.y);
    s4 += bf_lo(b.z); s5 += bf_hi(b.z); s6 += bf_lo(b.w); s7 += bf_hi(b.w);
    s0 += bf_lo(c.x); s1 += bf_hi(c.x); s2 += bf_lo(c.y); s3 += bf_hi(c.y);
    s4 += bf_lo(c.z); s5 += bf_hi(c.z); s6 += bf_lo(c.w); s7 += bf_hi(c.w);
    s0 += bf_lo(d.x); s1 += bf_hi(d.x); s2 += bf_lo(d.y); s3 += bf_hi(d.y);
    s4 += bf_lo(d.z); s5 += bf_hi(d.z); s6 += bf_lo(d.w); s7 += bf_hi(d.w);
  }
  for (; i < end; i += 8) {
    if (i + slot < end) {
      uint4 a = hb4[csr[i + slot] * 8 + fq];
      s0 += bf_lo(a.x); s1 += bf_hi(a.x); s2 += bf_lo(a.y); s3 += bf_hi(a.y);
      s4 += bf_lo(a.z); s5 += bf_hi(a.z); s6 += bf_lo(a.w); s7 += bf_hi(a.w);
    }
  }
#pragma unroll
  for (int off = 8; off <= 32; off <<= 1) {
    s0 += __shfl_xor(s0, off); s1 += __shfl_xor(s1, off);
    s2 += __shfl_xor(s2, off); s3 += __shfl_xor(s3, off);
    s4 += __shfl_xor(s4, off); s5 += __shfl_xor(s5, off);
    s6 += __shfl_xor(s6, off); s7 += __shfl_xor(s7, off);
  }
  if (slot == 0) {
    float invd = (deg > 0) ? 1.f / (float)deg : 0.f;
    uint4 o;
    o.x = pack2bf(s0 * invd, s1 * invd);
    o.y = pack2bf(s2 * invd, s3 * invd);
    o.z = pack2bf(s4 * invd, s5 * invd);
    o.w = pack2bf(s6 * invd, s7 * invd);
    mean2[n * 8 + fq] = o;
  }
}

// ---------------- MFMA GEMM kernels (wave = 16-node tile) --------------------
// A-frag: lane l holds A[l&15][(l>>4)*8+e]; B from transposed W (16B loads);
// C/D: lane l, reg r -> row (l>>4)*4+r, col l&15  [verified m89/m91 + R5 pass].

__global__ void __launch_bounds__(256) k_gemm1(
    const ushort* __restrict__ mean1, const ushort* __restrict__ xb,
    const ushort* __restrict__ W1T, const float* __restrict__ bl,
    ushort* __restrict__ h1b)
{
  int wave = (blockIdx.x * blockDim.x + threadIdx.x) >> 6;
  if (wave >= N_TILES) return;
  int lane = threadIdx.x & 63;
  int lc = lane & 15;
  int lg = lane >> 4;
  int n0 = wave * 16;

  bf16x8 bfr[4][2];
#pragma unroll
  for (int j = 0; j < 4; ++j)
#pragma unroll
    for (int kk = 0; kk < 2; ++kk)
      bfr[j][kk] = *(const bf16x8*)(W1T + (j * 16 + lc) * 64 + kk * 32 + lg * 8);

  f32x4 c[4];
#pragma unroll
  for (int j = 0; j < 4; ++j) {
    float b = bl[j * 16 + lc];
    c[j][0] = b; c[j][1] = b; c[j][2] = b; c[j][3] = b;
  }

  bf16x8 a0 = *(const bf16x8*)(mean1 + (n0 + lc) * 32 + lg * 8);
  bf16x8 a1 = *(const bf16x8*)(xb    + (n0 + lc) * 32 + lg * 8);
#pragma unroll
  for (int j = 0; j < 4; ++j) {
    c[j] = __builtin_amdgcn_mfma_f32_16x16x32_bf16(a0, bfr[j][0], c[j], 0, 0, 0);
    c[j] = __builtin_amdgcn_mfma_f32_16x16x32_bf16(a1, bfr[j][1], c[j], 0, 0, 0);
  }

#pragma unroll
  for (int j = 0; j < 4; ++j)
#pragma unroll
    for (int r = 0; r < 4; ++r) {
      int node = n0 + lg * 4 + r;
      h1b[node * 64 + j * 16 + lc] = f2bf(fmaxf(c[j][r], 0.f));
    }
}

__global__ void __launch_bounds__(256) k_gemm2(
    const ushort* __restrict__ mean2, const ushort* __restrict__ h1b,
    const ushort* __restrict__ W2T, const float* __restrict__ bl,
    const float* __restrict__ Wh, float* __restrict__ u, float* __restrict__ v)
{
  int wave = (blockIdx.x * blockDim.x + threadIdx.x) >> 6;
  if (wave >= N_TILES) return;
  int lane = threadIdx.x & 63;
  int lc = lane & 15;
  int lg = lane >> 4;
  int n0 = wave * 16;

  bf16x8 bfr[4][4];
#pragma unroll
  for (int j = 0; j < 4; ++j)
#pragma unroll
    for (int kk = 0; kk < 4; ++kk)
      bfr[j][kk] = *(const bf16x8*)(W2T + (j * 16 + lc) * 128 + kk * 32 + lg * 8);

  f32x4 c[4];
#pragma unroll
  for (int j = 0; j < 4; ++j) {
    float b = bl[j * 16 + lc];
    c[j][0] = b; c[j][1] = b; c[j][2] = b; c[j][3] = b;
  }

  bf16x8 a0 = *(const bf16x8*)(mean2 + (n0 + lc) * 64 + lg * 8);
  bf16x8 a1 = *(const bf16x8*)(mean2 + (n0 + lc) * 64 + 32 + lg * 8);
  bf16x8 a2 = *(const bf16x8*)(h1b   + (n0 + lc) * 64 + lg * 8);
  bf16x8 a3 = *(const bf16x8*)(h1b   + (n0 + lc) * 64 + 32 + lg * 8);
#pragma unroll
  for (int j = 0; j < 4; ++j) {
    c[j] = __builtin_amdgcn_mfma_f32_16x16x32_bf16(a0, bfr[j][0], c[j], 0, 0, 0);
    c[j] = __builtin_amdgcn_mfma_f32_16x16x32_bf16(a1, bfr[j][1], c[j], 0, 0, 0);
    c[j] = __builtin_amdgcn_mfma_f32_16x16x32_bf16(a2, bfr[j][2], c[j], 0, 0, 0);
    c[j] = __builtin_amdgcn_mfma_f32_16x16x32_bf16(a3, bfr[j][3], c[j], 0, 0, 0);
  }

  float pu0 = 0.f, pu1 = 0.f, pu2 = 0.f, pu3 = 0.f;
  float pv0 = 0.f, pv1 = 0.f, pv2 = 0.f, pv3 = 0.f;
#pragma unroll
  for (int j = 0; j < 4; ++j) {
    float wu = Wh[j * 16 + lc];
    float wv = Wh[64 + j * 16 + lc];
    float r0 = fmaxf(c[j][0], 0.f), r1 = fmaxf(c[j][1], 0.f);
    float r2 = fmaxf(c[j][2], 0.f), r3 = fmaxf(c[j][3], 0.f);
    pu0 = fmaf(r0, wu, pu0); pv0 = fmaf(r0, wv, pv0);
    pu1 = fmaf(r1, wu, pu1); pv1 = fmaf(r1, wv, pv1);
    pu2 = fmaf(r2, wu, pu2); pv2 = fmaf(r2, wv, pv2);
    pu3 = fmaf(r3, wu, pu3); pv3 = fmaf(r3, wv, pv3);
  }
#pragma unroll
  for (int off = 1; off <= 8; off <<= 1) {
    pu0 += __shfl_xor(pu0, off); pv0 += __shfl_xor(pv0, off);
    pu1 += __shfl_xor(pu1, off); pv1 += __shfl_xor(pv1, off);
    pu2 += __shfl_xor(pu2, off); pv2 += __shfl_xor(pv2, off);
    pu3 += __shfl_xor(pu3, off); pv3 += __shfl_xor(pv3, off);
  }
  if (lc == 0) {
    int node = n0 + lg * 4;
    u[node]     = pu0; v[node]     = pv0;
    u[node + 1] = pu1; v[node + 1] = pv1;
    u[node + 2] = pu2; v[node + 2] = pv2;
    u[node + 3] = pu3; v[node + 3] = pv3;
  }
}

// ---------------- edge scorer: table lookup only ----------------

__global__ void __launch_bounds__(256) k_edge_lite(
    const int2* __restrict__ pairs, const float* __restrict__ u,
    const float* __restrict__ v, const float* __restrict__ bh,
    float* __restrict__ out)
{
  int e = blockIdx.x * blockDim.x + threadIdx.x;
  if (e < N_PAIRS) {
    int2 pr = pairs[e];
    out[e] = u[pr.x] + v[pr.y] + bh[0];
  }
}

// ---------------- launch ----------------

extern "C" void kernel_launch(void* const* d_in, const int* in_sizes, int n_in,
                              void* d_out, int out_size, void* d_ws, size_t ws_size,
                              hipStream_t stream)
{
  const float* x   = (const float*)d_in[0];
  const int*   ei  = (const int*)d_in[1];
  const int* pairs = (const int*)d_in[2];
  const float* Wl1 = (const float*)d_in[3];
  const float* bl1 = (const float*)d_in[4];
  const float* Wr1 = (const float*)d_in[5];
  const float* Wl2 = (const float*)d_in[6];
  const float* bl2 = (const float*)d_in[7];
  const float* Wr2 = (const float*)d_in[8];
  const float* Wh  = (const float*)d_in[9];
  const float* bh  = (const float*)d_in[10];
  float* out = (float*)d_out;

  const int* src = ei;             // edge_index[0]
  const int* dst = ei + N_EDGES;   // edge_index[1]

  char* p = (char*)d_ws;
  auto alloc = [&](size_t bytes) {
    char* r = p;
    p += (bytes + 255) & ~(size_t)255;
    return r;
  };
  int*    woff        = (int*)alloc((size_t)NBUCK * 4);
  int*    bucket_data = (int*)alloc((size_t)NBUCK * CAP * 4);     // 13.6 MB (reused as mean2)
  int*    csr         = (int*)alloc((size_t)NBUCK * CAP * 4);     // 13.6 MB
  int*    row_beg     = (int*)alloc((size_t)N_NODES * 4);
  int*    row_end     = (int*)alloc((size_t)N_NODES * 4);
  ushort* xb          = (ushort*)alloc((size_t)N_NODES * 32 * 2); // 6.4 MB
  ushort* mean1       = (ushort*)alloc((size_t)N_NODES * 32 * 2); // 6.4 MB
  ushort* h1b         = (ushort*)alloc((size_t)N_NODES * 64 * 2); // 12.8 MB
  ushort* W1T         = (ushort*)alloc(64 * 64 * 2);
  ushort* W2T         = (ushort*)alloc(64 * 128 * 2);
  float*  uu          = (float*)alloc((size_t)N_NODES * 4);
  float*  vv          = (float*)alloc((size_t)N_NODES * 4);
  ushort* mean2       = (ushort*)bucket_data;   // dead after k_bucket_csr

  k_prep<<<(N_NODES * 8 + 255) / 256, 256, 0, stream>>>(
      x, Wl1, Wr1, Wl2, Wr2, xb, W1T, W2T, woff);
  k_binning<<<NCHB, 256, 0, stream>>>(src, dst, woff, bucket_data);
  k_bucket_csr<<<NBUCK, 512, 0, stream>>>(woff, bucket_data, csr, row_beg, row_end);

  k_gather1<<<(N_NODES * 64) / 256, 256, 0, stream>>>(
      (const uint4*)xb, row_beg, row_end, csr, (uint4*)mean1);
  k_gemm1<<<(N_TILES * 64 + 255) / 256, 256, 0, stream>>>(mean1, xb, W1T, bl1, h1b);
  k_gather2<<<(N_NODES * 64) / 256, 256, 0, stream>>>(
      (const uint4*)h1b, row_beg, row_end, csr, (uint4*)mean2);
  k_gemm2<<<(N_TILES * 64 + 255) / 256, 256, 0, stream>>>(
      mean2, h1b, W2T, bl2, Wh, uu, vv);
  k_edge_lite<<<(N_PAIRS + 255) / 256, 256, 0, stream>>>(
      (const int2*)pairs, uu, vv, bh, out);
}